// Round 3
// baseline (212.690 us; speedup 1.0000x reference)
//
#include <hip/hip_runtime.h>
#include <cmath>

// Problem constants (fixed by the reference).
constexpr int B  = 4096;
constexpr int D  = 768;
constexpr int P  = 96;
constexpr int C  = 256;
constexpr int SD = 8;    // D / P

constexpr int TPB  = 256;           // 4 waves per block
constexpr int ROWS = 2;             // rows per thread
constexpr int SEGS = 4;             // 4 segments x 64 centroids = 256
constexpr int RPB  = TPB * ROWS;    // 512 rows per block

// ---- numpy fp32 emulation helpers (exact path only, validated absmax=0) ----
__device__ __forceinline__ float tree8(float q0, float q1, float q2, float q3,
                                       float q4, float q5, float q6, float q7)
{
#pragma clang fp contract(off)
    return ((q0 + q1) + (q2 + q3)) + ((q4 + q5) + (q6 + q7));
}

__device__ __forceinline__ float proba_np(const float* __restrict__ cbf,
                                          const float* __restrict__ csq,
                                          int c, float4 va, float4 vb, float vsq)
{
#pragma clang fp contract(off)
    float4 ca = ((const float4*)cbf)[2 * c];
    float4 cb = ((const float4*)cbf)[2 * c + 1];
    float p0 = va.x * ca.x, p1 = va.y * ca.y, p2 = va.z * ca.z, p3 = va.w * ca.w;
    float p4 = vb.x * cb.x, p5 = vb.y * cb.y, p6 = vb.z * cb.z, p7 = vb.w * cb.w;
    float l0 = p0 + p4, l1 = p1 + p5, l2 = p2 + p6, l3 = p3 + p7;
    float vc = (l0 + l2) + (l1 + l3);
    float tt = vsq - 2.0f * vc;
    float u  = tt + csq[c];
    return -u;
}

// Exact numpy-order argmax incl. softmax tie path. Identical arithmetic to the
// validated kernel (absmax == 0.0). Rare (delta-guard) path only.
__device__ __forceinline__
int exact_search(const float* __restrict__ cbf, const float* __restrict__ csq,
                 float4 va, float4 vb, float vsq)
{
#pragma clang fp contract(off)
    float best = -3.402823466e38f, second = -3.402823466e38f;
    int bi = 0;
    for (int c = 0; c < C; ++c) {
        float pr = proba_np(cbf, csq, c, va, vb, vsq);
        if (pr > best)        { second = best; best = pr; bi = c; }
        else if (pr > second) { second = pr; }
    }
    int idx = bi;

    if (best - second <= 1.0e-6f) {
        float m = best;
        float r0[8] = {0,0,0,0,0,0,0,0};
        float r1[8] = {0,0,0,0,0,0,0,0};
        for (int cg = 0; cg < 16; ++cg) {
            #pragma unroll
            for (int j = 0; j < 8; ++j) {
                float pr = proba_np(cbf, csq, cg * 8 + j, va, vb, vsq);
                r0[j] += expf(pr - m);
            }
        }
        for (int cg = 16; cg < 32; ++cg) {
            #pragma unroll
            for (int j = 0; j < 8; ++j) {
                float pr = proba_np(cbf, csq, cg * 8 + j, va, vb, vsq);
                r1[j] += expf(pr - m);
            }
        }
        float sum = tree8(r0[0],r0[1],r0[2],r0[3],r0[4],r0[5],r0[6],r0[7])
                  + tree8(r1[0],r1[1],r1[2],r1[3],r1[4],r1[5],r1[6],r1[7]);
        float abest = -1.0f;
        int   ai    = 0;
        for (int c = 0; c < C; ++c) {
            float pr = proba_np(cbf, csq, c, va, vb, vsq);
            float e  = expf(pr - m);
            float a  = e / sum;
            if (a > abest) { abest = a; ai = c; }
        }
        idx = ai;
    }
    return idx;
}

// Broadcast lane `i`'s value to all lanes (uniform index -> v_readlane to SGPR).
// Pure register op: no LDS/VMEM, no waitcnt, no latency.
__device__ __forceinline__ float rdlane(float x, int i)
{
    return __int_as_float(__builtin_amdgcn_readlane(__float_as_int(x), i));
}

// RESIDENCY-IMMUNE STRUCTURE (round 3).
// Evidence from rounds 0-2: all variants ~125-155us with VALUBusy 17-28% and
// OccupancyPercent 9-15% => effectively ~1 block resident per CU, blocks
// serialized, so per-block latency chains (LDS->FMA or scratch) are exposed
// with no co-resident waves to hide them. Fix: a hot loop with ZERO memory
// operations and ZERO inter-wave coupling, so even 1 wave/SIMD runs at issue
// rate.
//   - Each wave holds ALL 256 centroids in registers: 4 segments, lane l owns
//     centroid s*64+l (4x(8+1) = 36 VGPRs).
//   - Each thread scans c = 0..255 (ascending: seg-major) for its ROWS rows,
//     broadcasting centroid data with 9 readlanes per centroid.
//   - No merge phase, no part_* LDS, no mid-kernel barrier. One barrier after
//     the loop orders cbf/csqn staging for the exact path + output gather.
// Scan order + strict-'>' branchless top-2 + fmaf chain + (-0.5*csq) seed are
// bit-identical to the validated merged version => same (best,second,idx),
// same 2e-5 guard behavior, same exact fallback => absmax stays 0.
__global__ __launch_bounds__(TPB, 4)
void pq_regscan_kernel(const float* __restrict__ vecs,
                       const float* __restrict__ codebook,
                       float* __restrict__ out)
{
    __shared__ float cbf [C * SD];   // 8 KB codebook[p] (exact path + gather)
    __shared__ float csqn[C];        // 1 KB ||c||^2 numpy order (exact path)

    const int p = blockIdx.x;
    const int t = threadIdx.x;
    const int w = t >> 6;            // wave id 0..3 (uniform per wave)
    const int l = t & 63;            // lane id
    const int rowbase = blockIdx.y * RPB;

    // ---- per-lane centroid registers (coalesced 32 B/lane per segment) ----
    float4 cA[SEGS], cB[SEGS];
    #pragma unroll
    for (int s = 0; s < SEGS; ++s) {
        const float* cg = codebook + ((size_t)p * C + s * 64 + l) * SD;
        cA[s] = ((const float4*)cg)[0];
        cB[s] = ((const float4*)cg)[1];
    }

    // ---- this thread's rows ----
    float4 va[ROWS], vb[ROWS];
    #pragma unroll
    for (int r = 0; r < ROWS; ++r) {
        const float* vptr = vecs + (size_t)(rowbase + r * TPB + t) * D + (size_t)p * SD;
        va[r] = ((const float4*)vptr)[0];
        vb[r] = ((const float4*)vptr)[1];
    }

    // ---- ||c||^2 per owned centroid (numpy tree order) + fast seeds ----
    float ch[SEGS], q[SEGS];
    #pragma unroll
    for (int s = 0; s < SEGS; ++s) {
#pragma clang fp contract(off)
        float q0 = cA[s].x*cA[s].x, q1 = cA[s].y*cA[s].y;
        float q2 = cA[s].z*cA[s].z, q3 = cA[s].w*cA[s].w;
        float q4 = cB[s].x*cB[s].x, q5 = cB[s].y*cB[s].y;
        float q6 = cB[s].z*cB[s].z, q7 = cB[s].w*cB[s].w;
        q[s]  = tree8(q0,q1,q2,q3,q4,q5,q6,q7);
        ch[s] = -0.5f * q[s];
    }

    // ---- stage centroid t (= segment w, lane l) into LDS; wave-uniform select
    //      with compile-time indices (no runtime-indexed arrays -> no scratch)
    {
        float4 sa = cA[0], sb = cB[0];
        float  sq = q[0];
        if (w == 1) { sa = cA[1]; sb = cB[1]; sq = q[1]; }
        if (w == 2) { sa = cA[2]; sb = cB[2]; sq = q[2]; }
        if (w == 3) { sa = cA[3]; sb = cB[3]; sq = q[3]; }
        ((float4*)cbf)[2 * t]     = sa;
        ((float4*)cbf)[2 * t + 1] = sb;
        csqn[t] = sq;
    }

    // ---- register-only scan over all 256 centroids (branchless top-2) ----
    float best[ROWS], second[ROWS];
    int   bi[ROWS];
    #pragma unroll
    for (int r = 0; r < ROWS; ++r) {
        best[r] = -3.402823466e38f; second[r] = -3.402823466e38f; bi[r] = 0;
    }

    #pragma unroll
    for (int s = 0; s < SEGS; ++s) {
        const float4 A  = cA[s];
        const float4 Bb = cB[s];
        const float  H  = ch[s];
        #pragma unroll 4
        for (int ci = 0; ci < 64; ++ci) {
            const int c = s * 64 + ci;           // ascending 0..255 overall
            float cax = rdlane(A.x,  ci), cay = rdlane(A.y,  ci);
            float caz = rdlane(A.z,  ci), caw = rdlane(A.w,  ci);
            float cbx = rdlane(Bb.x, ci), cby = rdlane(Bb.y, ci);
            float cbz = rdlane(Bb.z, ci), cbw = rdlane(Bb.w, ci);
            float chc = rdlane(H,    ci);
            #pragma unroll
            for (int r = 0; r < ROWS; ++r) {
                float sv = fmaf(va[r].x, cax, chc);
                sv = fmaf(va[r].y, cay, sv);
                sv = fmaf(va[r].z, caz, sv);
                sv = fmaf(va[r].w, caw, sv);
                sv = fmaf(vb[r].x, cbx, sv);
                sv = fmaf(vb[r].y, cby, sv);
                sv = fmaf(vb[r].z, cbz, sv);
                sv = fmaf(vb[r].w, cbw, sv);
                bool gt = sv > best[r];
                second[r] = fmaxf(second[r], fminf(sv, best[r]));
                bi[r]     = gt ? c : bi[r];
                best[r]   = fmaxf(sv, best[r]);
            }
        }
    }

    __syncthreads();   // cbf/csqn staging visible for exact path + gather

    // ---- finalize each row: guard -> (rare) exact path -> gather + store ----
    #pragma unroll
    for (int r = 0; r < ROWS; ++r) {
        const int row = rowbase + r * TPB + t;
        int idx = bi[r];
        if (best[r] - second[r] <= 2.0e-5f) {     // near-tie: exact numpy path
#pragma clang fp contract(off)
            float q0 = va[r].x*va[r].x, q1 = va[r].y*va[r].y;
            float q2 = va[r].z*va[r].z, q3 = va[r].w*va[r].w;
            float q4 = vb[r].x*vb[r].x, q5 = vb[r].y*vb[r].y;
            float q6 = vb[r].z*vb[r].z, q7 = vb[r].w*vb[r].w;
            float vsq = tree8(q0,q1,q2,q3,q4,q5,q6,q7);
            idx = exact_search(cbf, csqn, va[r], vb[r], vsq);
        }
        float4 o0 = ((const float4*)cbf)[2 * idx];
        float4 o1 = ((const float4*)cbf)[2 * idx + 1];
        float4* op = (float4*)(out + (size_t)row * D + (size_t)p * SD);
        op[0] = o0;
        op[1] = o1;
    }
}

extern "C" void kernel_launch(void* const* d_in, const int* in_sizes, int n_in,
                              void* d_out, int out_size, void* d_ws, size_t ws_size,
                              hipStream_t stream)
{
    const float* vecs     = (const float*)d_in[0];  // [B, D] fp32
    const float* codebook = (const float*)d_in[1];  // [P, C, SD] fp32
    float*       out      = (float*)d_out;          // [B, D] fp32

    dim3 grid(P, B / RPB);   // (96, 8) -> 768 blocks x 4 waves, 3 blocks/CU
    dim3 block(TPB);
    pq_regscan_kernel<<<grid, block, 0, stream>>>(vecs, codebook, out);
}

// Round 4
// 197.652 us; speedup vs baseline: 1.0761x; 1.0761x over previous
//
#include <hip/hip_runtime.h>
#include <cmath>

// Problem constants (fixed by the reference).
constexpr int B  = 4096;
constexpr int D  = 768;
constexpr int P  = 96;
constexpr int C  = 256;
constexpr int SD = 8;    // D / P

constexpr int TPB  = 256;      // 4 waves per block
constexpr int WPB  = 4;        // waves per block (centroid split)
constexpr int CPW  = C / WPB;  // 64 centroids per wave
constexpr int ROWS = 4;        // rows per thread

// ---- numpy fp32 emulation helpers (exact path only, validated absmax=0) ----
__device__ __forceinline__ float tree8(float q0, float q1, float q2, float q3,
                                       float q4, float q5, float q6, float q7)
{
#pragma clang fp contract(off)
    return ((q0 + q1) + (q2 + q3)) + ((q4 + q5) + (q6 + q7));
}

// numpy-order score. csq is recomputed inline with the IDENTICAL ops/order the
// validated kernel used when staging csqn (same inputs, same tree -> same bits),
// so dropping the csqn LDS array does not change any exact-path value.
__device__ __forceinline__ float proba_np(const float* __restrict__ cbf,
                                          int c, float4 va, float4 vb, float vsq)
{
#pragma clang fp contract(off)
    float4 ca = ((const float4*)cbf)[2 * c];
    float4 cb = ((const float4*)cbf)[2 * c + 1];
    float q0 = ca.x*ca.x, q1 = ca.y*ca.y, q2 = ca.z*ca.z, q3 = ca.w*ca.w;
    float q4 = cb.x*cb.x, q5 = cb.y*cb.y, q6 = cb.z*cb.z, q7 = cb.w*cb.w;
    float csq = tree8(q0,q1,q2,q3,q4,q5,q6,q7);
    float p0 = va.x * ca.x, p1 = va.y * ca.y, p2 = va.z * ca.z, p3 = va.w * ca.w;
    float p4 = vb.x * cb.x, p5 = vb.y * cb.y, p6 = vb.z * cb.z, p7 = vb.w * cb.w;
    float l0 = p0 + p4, l1 = p1 + p5, l2 = p2 + p6, l3 = p3 + p7;
    float vc = (l0 + l2) + (l1 + l3);
    float tt = vsq - 2.0f * vc;
    float u  = tt + csq;
    return -u;
}

// Exact numpy-order argmax incl. softmax tie path. Identical arithmetic to the
// validated kernel (absmax == 0.0). Rare (delta-guard) path only.
__device__ __forceinline__
int exact_search(const float* __restrict__ cbf,
                 float4 va, float4 vb, float vsq)
{
#pragma clang fp contract(off)
    float best = -3.402823466e38f, second = -3.402823466e38f;
    int bi = 0;
    for (int c = 0; c < C; ++c) {
        float pr = proba_np(cbf, c, va, vb, vsq);
        if (pr > best)        { second = best; best = pr; bi = c; }
        else if (pr > second) { second = pr; }
    }
    int idx = bi;

    if (best - second <= 1.0e-6f) {
        float m = best;
        float r0[8] = {0,0,0,0,0,0,0,0};
        float r1[8] = {0,0,0,0,0,0,0,0};
        for (int cg = 0; cg < 16; ++cg) {
            #pragma unroll
            for (int j = 0; j < 8; ++j) {
                float pr = proba_np(cbf, cg * 8 + j, va, vb, vsq);
                r0[j] += expf(pr - m);
            }
        }
        for (int cg = 16; cg < 32; ++cg) {
            #pragma unroll
            for (int j = 0; j < 8; ++j) {
                float pr = proba_np(cbf, cg * 8 + j, va, vb, vsq);
                r1[j] += expf(pr - m);
            }
        }
        float sum = tree8(r0[0],r0[1],r0[2],r0[3],r0[4],r0[5],r0[6],r0[7])
                  + tree8(r1[0],r1[1],r1[2],r1[3],r1[4],r1[5],r1[6],r1[7]);
        float abest = -1.0f;
        int   ai    = 0;
        for (int c = 0; c < C; ++c) {
            float pr = proba_np(cbf, c, va, vb, vsq);
            float e  = expf(pr - m);
            float a  = e / sum;
            if (a > abest) { abest = a; ai = c; }
        }
        idx = ai;
    }
    return idx;
}

// Broadcast lane i's value to all lanes (uniform index -> v_readlane). Pure
// register op, no latency.
__device__ __forceinline__ float rdlane(float x, int i)
{
    return __int_as_float(__builtin_amdgcn_readlane(__float_as_int(x), i));
}

// ROUND 4: round-0 merged structure (best measured: 125us, clean 12.3MB write
// traffic) with the occupancy promise maxed out.
// Evidence rounds 0-3: OccupancyPercent/VALUBusy/duration all scale with the
// __launch_bounds__ waves-per-EU promise (6->13.1%/22%/125us vs 4->9%/17%/154us
// on the identical structure). So: promise 8 (= 8 blocks/CU = HW max 32
// waves/CU), and make 8 blocks FIT:
//   - LDS cut 22.5KB -> 20KB (= 160/8 exactly): csqn/csqh arrays dropped.
//     ch lives in a register (lane l of wave w owns centroid 64w+l), broadcast
//     by 1 readlane per centroid; exact path recomputes csq inline (bit-same).
//   - VGPR cap 64: hot-loop live set ~55 (16 va/vb + 12 trackers + dual
//     operand set + addresses). Fits without spill.
// Inner loop processes 2 centroids x 4 rows = 8 independent FMA chains
// (round 0 had 4) to fill the 4-cy dependency bubbles even at low residency.
// Tracker updates are applied strictly in centroid order (c, then c+1), so the
// (best, second, idx) sequence is bit-identical to the validated scalar scan;
// merge, 2e-5 guard, exact path and store are unchanged from round 0.
__global__ __launch_bounds__(TPB, 8)
void pq_split_kernel(const float* __restrict__ vecs,
                     const float* __restrict__ codebook,
                     float* __restrict__ out)
{
    __shared__ float  cbf [C * SD];            // 8 KB codebook[p]
    __shared__ float2 part_bs[WPB][ROWS][64];  // 8 KB (best, second)
    __shared__ int    part_i [WPB][ROWS][64];  // 4 KB argmax per range
                                               // total 20 KB -> 8 blocks/CU

    const int p = blockIdx.x;
    const int t = threadIdx.x;
    const int w = t >> 6;          // wave id 0..3
    const int l = t & 63;          // lane id
    const int rowbase = blockIdx.y * (64 * ROWS);

    // ---- own-centroid load (centroid index == t, coalesced 32 B/lane) ----
    const float* cg = codebook + ((size_t)p * C + t) * SD;
    float4 cra = ((const float4*)cg)[0];
    float4 crb = ((const float4*)cg)[1];

    // ---- this thread's ROWS sub-vectors (round-0 row mapping) ----
    float4 va[ROWS], vb[ROWS];
    #pragma unroll
    for (int r = 0; r < ROWS; ++r) {
        const float* vptr = vecs + (size_t)(rowbase + 64 * r + l) * D + (size_t)p * SD;
        va[r] = ((const float4*)vptr)[0];
        vb[r] = ((const float4*)vptr)[1];
    }

    // ---- fast seed for own centroid: ch = -0.5*||c||^2 (numpy tree order) ----
    float ch_own;
    {
#pragma clang fp contract(off)
        float q0 = cra.x*cra.x, q1 = cra.y*cra.y, q2 = cra.z*cra.z, q3 = cra.w*cra.w;
        float q4 = crb.x*crb.x, q5 = crb.y*crb.y, q6 = crb.z*crb.z, q7 = crb.w*crb.w;
        ch_own = -0.5f * tree8(q0,q1,q2,q3,q4,q5,q6,q7);
    }

    // ---- stage codebook[p] into LDS from the already-loaded regs ----
    ((float4*)cbf)[2 * t]     = cra;
    ((float4*)cbf)[2 * t + 1] = crb;
    __syncthreads();

    // ---- fast scoring: this wave's 64 centroids, 2 per iteration ----
    float best[ROWS], second[ROWS];
    int   bi[ROWS];
    #pragma unroll
    for (int r = 0; r < ROWS; ++r) {
        best[r] = -3.402823466e38f; second[r] = -3.402823466e38f; bi[r] = 0;
    }

    const int c0 = w * CPW;
    for (int ci = 0; ci < CPW; ci += 2) {
        const int cidx0 = c0 + ci;
        const int cidx1 = c0 + ci + 1;
        float4 ca0 = ((const float4*)cbf)[2 * cidx0];     // wave-uniform bcast
        float4 cb0 = ((const float4*)cbf)[2 * cidx0 + 1];
        float4 ca1 = ((const float4*)cbf)[2 * cidx1];
        float4 cb1 = ((const float4*)cbf)[2 * cidx1 + 1];
        float  ch0 = rdlane(ch_own, ci);
        float  ch1 = rdlane(ch_own, ci + 1);

        float s0[ROWS], s1[ROWS];
        #pragma unroll
        for (int r = 0; r < ROWS; ++r) {        // 8 independent chains
            float s = fmaf(va[r].x, ca0.x, ch0);
            s = fmaf(va[r].y, ca0.y, s);
            s = fmaf(va[r].z, ca0.z, s);
            s = fmaf(va[r].w, ca0.w, s);
            s = fmaf(vb[r].x, cb0.x, s);
            s = fmaf(vb[r].y, cb0.y, s);
            s = fmaf(vb[r].z, cb0.z, s);
            s = fmaf(vb[r].w, cb0.w, s);
            s0[r] = s;
        }
        #pragma unroll
        for (int r = 0; r < ROWS; ++r) {
            float s = fmaf(va[r].x, ca1.x, ch1);
            s = fmaf(va[r].y, ca1.y, s);
            s = fmaf(va[r].z, ca1.z, s);
            s = fmaf(va[r].w, ca1.w, s);
            s = fmaf(vb[r].x, cb1.x, s);
            s = fmaf(vb[r].y, cb1.y, s);
            s = fmaf(vb[r].z, cb1.z, s);
            s = fmaf(vb[r].w, cb1.w, s);
            s1[r] = s;
        }
        // tracker updates strictly in centroid order: c, then c+1 (bit-exact
        // match to the sequential scan the guard was validated against)
        #pragma unroll
        for (int r = 0; r < ROWS; ++r) {
            bool gt = s0[r] > best[r];
            second[r] = fmaxf(second[r], fminf(s0[r], best[r]));
            bi[r]     = gt ? cidx0 : bi[r];
            best[r]   = fmaxf(s0[r], best[r]);
        }
        #pragma unroll
        for (int r = 0; r < ROWS; ++r) {
            bool gt = s1[r] > best[r];
            second[r] = fmaxf(second[r], fminf(s1[r], best[r]));
            bi[r]     = gt ? cidx1 : bi[r];
            best[r]   = fmaxf(s1[r], best[r]);
        }
    }

    // ---- publish partials ----
    #pragma unroll
    for (int r = 0; r < ROWS; ++r) {
        part_bs[w][r][l] = make_float2(best[r], second[r]);
        part_i [w][r][l] = bi[r];
    }
    __syncthreads();

    // ---- merge: thread t resolves row rowbase + t (its own j == w, lane l) ----
    {
        float Bst = -3.402823466e38f, Snd = -3.402823466e38f;
        int   I   = 0;
        #pragma unroll
        for (int ww = 0; ww < WPB; ++ww) {
            float2 bs = part_bs[ww][w][l];
            int    iw = part_i [ww][w][l];
            bool gt = bs.x > Bst;                 // strict, ascending ww:
            Snd = fmaxf(Snd, fminf(bs.x, Bst));   // first (smaller c) wins ties
            Snd = fmaxf(Snd, bs.y);
            I   = gt ? iw : I;
            Bst = fmaxf(Bst, bs.x);
        }

        const int row = rowbase + t;
        int idx = I;
        if (Bst - Snd <= 2.0e-5f) {               // near-tie: exact numpy path
#pragma clang fp contract(off)
            const float* vptr = vecs + (size_t)row * D + (size_t)p * SD;
            float4 xa = ((const float4*)vptr)[0];
            float4 xb = ((const float4*)vptr)[1];
            float q0 = xa.x*xa.x, q1 = xa.y*xa.y, q2 = xa.z*xa.z, q3 = xa.w*xa.w;
            float q4 = xb.x*xb.x, q5 = xb.y*xb.y, q6 = xb.z*xb.z, q7 = xb.w*xb.w;
            float vsq = tree8(q0,q1,q2,q3,q4,q5,q6,q7);
            idx = exact_search(cbf, xa, xb, vsq);
        }

        float4 o0 = ((const float4*)cbf)[2 * idx];
        float4 o1 = ((const float4*)cbf)[2 * idx + 1];
        float4* op = (float4*)(out + (size_t)row * D + (size_t)p * SD);
        op[0] = o0;
        op[1] = o1;
    }
}

extern "C" void kernel_launch(void* const* d_in, const int* in_sizes, int n_in,
                              void* d_out, int out_size, void* d_ws, size_t ws_size,
                              hipStream_t stream)
{
    const float* vecs     = (const float*)d_in[0];  // [B, D] fp32
    const float* codebook = (const float*)d_in[1];  // [P, C, SD] fp32
    float*       out      = (float*)d_out;          // [B, D] fp32

    dim3 grid(P, B / (64 * ROWS));   // (96, 16) -> 1536 blocks x 4 waves
    dim3 block(TPB);
    pq_split_kernel<<<grid, block, 0, stream>>>(vecs, codebook, out);
}

// Round 5
// 175.385 us; speedup vs baseline: 1.2127x; 1.1270x over previous
//
#include <hip/hip_runtime.h>
#include <cmath>

// Problem constants (fixed by the reference).
constexpr int B  = 4096;
constexpr int D  = 768;
constexpr int P  = 96;
constexpr int C  = 256;
constexpr int SD = 8;    // D / P

constexpr int TPB  = 256;   // 4 waves per block
constexpr int WPB  = 4;     // waves per block (centroid split)
constexpr int CPW  = C / WPB;  // 64 centroids per wave
constexpr int ROWS = 4;     // rows per thread (amortizes LDS centroid reads)

// ---- numpy fp32 emulation helpers (exact path only, validated absmax=0) ----
__device__ __forceinline__ float tree8(float q0, float q1, float q2, float q3,
                                       float q4, float q5, float q6, float q7)
{
#pragma clang fp contract(off)
    return ((q0 + q1) + (q2 + q3)) + ((q4 + q5) + (q6 + q7));
}

__device__ __forceinline__ float proba_np(const float* __restrict__ cbf,
                                          const float* __restrict__ csq,
                                          int c, float4 va, float4 vb, float vsq)
{
#pragma clang fp contract(off)
    float4 ca = ((const float4*)cbf)[2 * c];
    float4 cb = ((const float4*)cbf)[2 * c + 1];
    float p0 = va.x * ca.x, p1 = va.y * ca.y, p2 = va.z * ca.z, p3 = va.w * ca.w;
    float p4 = vb.x * cb.x, p5 = vb.y * cb.y, p6 = vb.z * cb.z, p7 = vb.w * cb.w;
    float l0 = p0 + p4, l1 = p1 + p5, l2 = p2 + p6, l3 = p3 + p7;
    float vc = (l0 + l2) + (l1 + l3);
    float tt = vsq - 2.0f * vc;
    float u  = tt + csq[c];
    return -u;
}

// Exact numpy-order argmax incl. softmax tie path. Byte-identical semantics to
// the round-1/2 kernel that measured absmax == 0.0. Rare (δ-guard) path only.
__device__ __attribute__((noinline))
int exact_search(const float* __restrict__ cbf, const float* __restrict__ csq,
                 float4 va, float4 vb, float vsq)
{
#pragma clang fp contract(off)
    float best = -3.402823466e38f, second = -3.402823466e38f;
    int bi = 0;
    for (int c = 0; c < C; ++c) {
        float pr = proba_np(cbf, csq, c, va, vb, vsq);
        if (pr > best)        { second = best; best = pr; bi = c; }
        else if (pr > second) { second = pr; }
    }
    int idx = bi;

    if (best - second <= 1.0e-6f) {
        float m = best;
        float r0[8] = {0,0,0,0,0,0,0,0};
        float r1[8] = {0,0,0,0,0,0,0,0};
        for (int cg = 0; cg < 16; ++cg) {
            #pragma unroll
            for (int j = 0; j < 8; ++j) {
                float pr = proba_np(cbf, csq, cg * 8 + j, va, vb, vsq);
                r0[j] += expf(pr - m);
            }
        }
        for (int cg = 16; cg < 32; ++cg) {
            #pragma unroll
            for (int j = 0; j < 8; ++j) {
                float pr = proba_np(cbf, csq, cg * 8 + j, va, vb, vsq);
                r1[j] += expf(pr - m);
            }
        }
        float sum = tree8(r0[0],r0[1],r0[2],r0[3],r0[4],r0[5],r0[6],r0[7])
                  + tree8(r1[0],r1[1],r1[2],r1[3],r1[4],r1[5],r1[6],r1[7]);
        float abest = -1.0f;
        int   ai    = 0;
        for (int c = 0; c < C; ++c) {
            float pr = proba_np(cbf, csq, c, va, vb, vsq);
            float e  = expf(pr - m);
            float a  = e / sum;
            if (a > abest) { abest = a; ai = c; }
        }
        idx = ai;
    }
    return idx;
}

// ROUND 5: byte-identical round-0 kernel (best measured: 125us rocprof,
// absmax=0, clean 12.3MB writes) with ONE change: the occupancy attribute.
//
// Diagnosis (rounds 0-4): VGPR_Count was 32-44 in every variant while the hot
// loop's live set is >=60 regs (va/vb=32 + trackers=12 + operands) => the
// allocator was rematerializing/spilling loop state every iteration. That
// traffic is L1/L2-resident (invisible in FETCH_SIZE) but its latency is on
// the critical path at ~1 wave/SIMD residency -> VALUBusy pinned ~20%, dur
// ~10x the 16us VALU floor, and total insensitivity to operand-delivery
// changes. Cause: __launch_bounds__' 2nd arg sets the MINIMUM waves/EU (an
// upper bound on regs); the backend then squeezes regs further chasing max
// occupancy. The correct lever is amdgpu_waves_per_eu(min, MAX): max=4 caps
// the occupancy target -> 512/4 = 128-VGPR budget -> live set stays resident.
__global__ __launch_bounds__(TPB)
__attribute__((amdgpu_waves_per_eu(1, 4)))
void pq_split_kernel(const float* __restrict__ vecs,
                     const float* __restrict__ codebook,
                     float* __restrict__ out)
{
    __shared__ float  cbf [C * SD];          // 8 KB codebook[p]
    __shared__ float  csqn[C];               // ||c||^2 numpy order (exact path)
    __shared__ float  csqh[C];               // -0.5*csq (fast seed)
    __shared__ float2 part_bs[WPB][ROWS][64];  // 8 KB (best, second)
    __shared__ int    part_i [WPB][ROWS][64];  // 4 KB argmax per range

    const int p = blockIdx.x;
    const int t = threadIdx.x;
    const int w = t >> 6;          // wave id 0..3
    const int l = t & 63;          // lane id
    const int rowbase = blockIdx.y * (64 * ROWS);

    // ---- stage codebook[p]: 512 float4, 2 per thread ----
    const float4* src = (const float4*)(codebook + (size_t)p * C * SD);
    ((float4*)cbf)[t]       = src[t];
    ((float4*)cbf)[t + 256] = src[t + 256];
    __syncthreads();

    // ---- csq (numpy order) + fast seed, 1 centroid per thread ----
    {
        const float* cc = cbf + t * SD;
        float q0 = cc[0]*cc[0], q1 = cc[1]*cc[1], q2 = cc[2]*cc[2], q3 = cc[3]*cc[3];
        float q4 = cc[4]*cc[4], q5 = cc[5]*cc[5], q6 = cc[6]*cc[6], q7 = cc[7]*cc[7];
        float s = tree8(q0,q1,q2,q3,q4,q5,q6,q7);
        csqn[t] = s;
        csqh[t] = -0.5f * s;
    }
    __syncthreads();

    // ---- load this thread's ROWS sub-vectors ----
    float4 va[ROWS], vb[ROWS];
    #pragma unroll
    for (int r = 0; r < ROWS; ++r) {
        const float* vptr = vecs + (size_t)(rowbase + 64 * r + l) * D + (size_t)p * SD;
        va[r] = ((const float4*)vptr)[0];
        vb[r] = ((const float4*)vptr)[1];
    }

    // ---- fast scoring over this wave's 64 centroids (branchless top-2) ----
    float best[ROWS], second[ROWS];
    int   bi[ROWS];
    #pragma unroll
    for (int r = 0; r < ROWS; ++r) {
        best[r] = -3.402823466e38f; second[r] = -3.402823466e38f; bi[r] = 0;
    }

    const int c0 = w * CPW;
    #pragma unroll 2
    for (int ci = 0; ci < CPW; ++ci) {
        const int c = c0 + ci;
        float4 ca = ((const float4*)cbf)[2 * c];     // wave-uniform broadcast
        float4 cb = ((const float4*)cbf)[2 * c + 1];
        float  ch = csqh[c];
        #pragma unroll
        for (int r = 0; r < ROWS; ++r) {
            float s = fmaf(va[r].x, ca.x, ch);
            s = fmaf(va[r].y, ca.y, s);
            s = fmaf(va[r].z, ca.z, s);
            s = fmaf(va[r].w, ca.w, s);
            s = fmaf(vb[r].x, cb.x, s);
            s = fmaf(vb[r].y, cb.y, s);
            s = fmaf(vb[r].z, cb.z, s);
            s = fmaf(vb[r].w, cb.w, s);
            bool gt = s > best[r];
            second[r] = fmaxf(second[r], fminf(s, best[r]));
            bi[r]     = gt ? c : bi[r];
            best[r]   = fmaxf(s, best[r]);
        }
    }

    // ---- publish partials ----
    #pragma unroll
    for (int r = 0; r < ROWS; ++r) {
        part_bs[w][r][l] = make_float2(best[r], second[r]);
        part_i [w][r][l] = bi[r];
    }
    __syncthreads();

    // ---- merge: thread t resolves row rowbase + t (its own j == w, lane l) ----
    {
        float Bst = -3.402823466e38f, Snd = -3.402823466e38f;
        int   I   = 0;
        #pragma unroll
        for (int ww = 0; ww < WPB; ++ww) {
            float2 bs = part_bs[ww][w][l];
            int    iw = part_i [ww][w][l];
            bool gt = bs.x > Bst;                 // strict, ascending ww:
            Snd = fmaxf(Snd, fminf(bs.x, Bst));   // first (smaller c) wins ties
            Snd = fmaxf(Snd, bs.y);
            I   = gt ? iw : I;
            Bst = fmaxf(Bst, bs.x);
        }

        const int row = rowbase + t;
        int idx = I;
        if (Bst - Snd <= 2.0e-5f) {               // near-tie: exact numpy path
            const float* vptr = vecs + (size_t)row * D + (size_t)p * SD;
            float4 xa = ((const float4*)vptr)[0];
            float4 xb = ((const float4*)vptr)[1];
            float q0 = xa.x*xa.x, q1 = xa.y*xa.y, q2 = xa.z*xa.z, q3 = xa.w*xa.w;
            float q4 = xb.x*xb.x, q5 = xb.y*xb.y, q6 = xb.z*xb.z, q7 = xb.w*xb.w;
            float vsq = tree8(q0,q1,q2,q3,q4,q5,q6,q7);
            idx = exact_search(cbf, csqn, xa, xb, vsq);
        }

        float4 o0 = ((const float4*)cbf)[2 * idx];
        float4 o1 = ((const float4*)cbf)[2 * idx + 1];
        float4* op = (float4*)(out + (size_t)row * D + (size_t)p * SD);
        op[0] = o0;
        op[1] = o1;
    }
}

extern "C" void kernel_launch(void* const* d_in, const int* in_sizes, int n_in,
                              void* d_out, int out_size, void* d_ws, size_t ws_size,
                              hipStream_t stream)
{
    const float* vecs     = (const float*)d_in[0];  // [B, D] fp32
    const float* codebook = (const float*)d_in[1];  // [P, C, SD] fp32
    float*       out      = (float*)d_out;          // [B, D] fp32

    dim3 grid(P, B / (64 * ROWS));   // (96, 16) -> 1536 blocks x 4 waves
    dim3 block(TPB);
    pq_split_kernel<<<grid, block, 0, stream>>>(vecs, codebook, out);
}

// Round 6
// 173.641 us; speedup vs baseline: 1.2249x; 1.0100x over previous
//
#include <hip/hip_runtime.h>
#include <cmath>

// Problem constants (fixed by the reference).
constexpr int B  = 4096;
constexpr int D  = 768;
constexpr int P  = 96;
constexpr int C  = 256;
constexpr int SD = 8;    // D / P

constexpr int TPB  = 256;   // 4 waves per block
constexpr int WPB  = 4;     // waves per block (centroid split)
constexpr int CPW  = C / WPB;  // 64 centroids per wave
constexpr int ROWS = 4;     // rows per thread (amortizes LDS centroid reads)

// ---- numpy fp32 emulation helpers (exact path only, validated absmax=0) ----
__device__ __forceinline__ float tree8(float q0, float q1, float q2, float q3,
                                       float q4, float q5, float q6, float q7)
{
#pragma clang fp contract(off)
    return ((q0 + q1) + (q2 + q3)) + ((q4 + q5) + (q6 + q7));
}

__device__ __forceinline__ float proba_np(const float* __restrict__ cbf,
                                          const float* __restrict__ csq,
                                          int c, float4 va, float4 vb, float vsq)
{
#pragma clang fp contract(off)
    float4 ca = ((const float4*)cbf)[2 * c];
    float4 cb = ((const float4*)cbf)[2 * c + 1];
    float p0 = va.x * ca.x, p1 = va.y * ca.y, p2 = va.z * ca.z, p3 = va.w * ca.w;
    float p4 = vb.x * cb.x, p5 = vb.y * cb.y, p6 = vb.z * cb.z, p7 = vb.w * cb.w;
    float l0 = p0 + p4, l1 = p1 + p5, l2 = p2 + p6, l3 = p3 + p7;
    float vc = (l0 + l2) + (l1 + l3);
    float tt = vsq - 2.0f * vc;
    float u  = tt + csq[c];
    return -u;
}

// Exact numpy-order argmax incl. softmax tie path. Byte-identical semantics to
// the validated kernel (absmax == 0.0). Rare (delta-guard) path only.
__device__ __attribute__((noinline))
int exact_search(const float* __restrict__ cbf, const float* __restrict__ csq,
                 float4 va, float4 vb, float vsq)
{
#pragma clang fp contract(off)
    float best = -3.402823466e38f, second = -3.402823466e38f;
    int bi = 0;
    for (int c = 0; c < C; ++c) {
        float pr = proba_np(cbf, csq, c, va, vb, vsq);
        if (pr > best)        { second = best; best = pr; bi = c; }
        else if (pr > second) { second = pr; }
    }
    int idx = bi;

    if (best - second <= 1.0e-6f) {
        float m = best;
        float r0[8] = {0,0,0,0,0,0,0,0};
        float r1[8] = {0,0,0,0,0,0,0,0};
        for (int cg = 0; cg < 16; ++cg) {
            #pragma unroll
            for (int j = 0; j < 8; ++j) {
                float pr = proba_np(cbf, csq, cg * 8 + j, va, vb, vsq);
                r0[j] += expf(pr - m);
            }
        }
        for (int cg = 16; cg < 32; ++cg) {
            #pragma unroll
            for (int j = 0; j < 8; ++j) {
                float pr = proba_np(cbf, csq, cg * 8 + j, va, vb, vsq);
                r1[j] += expf(pr - m);
            }
        }
        float sum = tree8(r0[0],r0[1],r0[2],r0[3],r0[4],r0[5],r0[6],r0[7])
                  + tree8(r1[0],r1[1],r1[2],r1[3],r1[4],r1[5],r1[6],r1[7]);
        float abest = -1.0f;
        int   ai    = 0;
        for (int c = 0; c < C; ++c) {
            float pr = proba_np(cbf, csq, c, va, vb, vsq);
            float e  = expf(pr - m);
            float a  = e / sum;
            if (a > abest) { abest = a; ai = c; }
        }
        idx = ai;
    }
    return idx;
}

// ROUND 6: R0 structure + EXPLICIT software pipelining of the hot loop.
// Evidence: R0-R5 falsified operand-source (LDS vs readlane), spill, and
// occupancy-promise theories; duration tracks residency, which is stuck at
// ~0.5-1 wave/SIMD, so the per-iteration ds_read latency (~120cy) is serially
// exposed (compiler never hoisted loads: 36-VGPR allocations). Fix the duty
// cycle WITHIN one wave: double-buffered batch-2 pipeline — issue the next 2
// centroids' 6 LDS reads, compute the current 2 (8 independent 8-deep FMA
// chains, ~208cy issue) while they fly. Load latency fully hidden without any
// co-resident waves. Registers: 2x18 buffers + 32 va/vb + 12 trackers ~= 95
// -> __launch_bounds__(256,5) (cap ~102, no spill). Tracker updates stay
// strictly per-row c-then-c+1 => (best,second,idx) bit-identical to the
// validated scan; merge, 2e-5 guard, exact path, store unchanged from R0.
__global__ __launch_bounds__(TPB, 5)
void pq_split_kernel(const float* __restrict__ vecs,
                     const float* __restrict__ codebook,
                     float* __restrict__ out)
{
    __shared__ float  cbf [C * SD];          // 8 KB codebook[p]
    __shared__ float  csqn[C];               // ||c||^2 numpy order (exact path)
    __shared__ float  csqh[C];               // -0.5*csq (fast seed)
    __shared__ float2 part_bs[WPB][ROWS][64];  // 8 KB (best, second)
    __shared__ int    part_i [WPB][ROWS][64];  // 4 KB argmax per range

    const int p = blockIdx.x;
    const int t = threadIdx.x;
    const int w = t >> 6;          // wave id 0..3
    const int l = t & 63;          // lane id
    const int rowbase = blockIdx.y * (64 * ROWS);

    // ---- stage codebook[p]: 512 float4, 2 per thread ----
    const float4* src = (const float4*)(codebook + (size_t)p * C * SD);
    ((float4*)cbf)[t]       = src[t];
    ((float4*)cbf)[t + 256] = src[t + 256];
    __syncthreads();

    // ---- csq (numpy order) + fast seed, 1 centroid per thread ----
    {
        const float* cc = cbf + t * SD;
        float q0 = cc[0]*cc[0], q1 = cc[1]*cc[1], q2 = cc[2]*cc[2], q3 = cc[3]*cc[3];
        float q4 = cc[4]*cc[4], q5 = cc[5]*cc[5], q6 = cc[6]*cc[6], q7 = cc[7]*cc[7];
        float s = tree8(q0,q1,q2,q3,q4,q5,q6,q7);
        csqn[t] = s;
        csqh[t] = -0.5f * s;
    }
    __syncthreads();

    // ---- load this thread's ROWS sub-vectors ----
    float4 va[ROWS], vb[ROWS];
    #pragma unroll
    for (int r = 0; r < ROWS; ++r) {
        const float* vptr = vecs + (size_t)(rowbase + 64 * r + l) * D + (size_t)p * SD;
        va[r] = ((const float4*)vptr)[0];
        vb[r] = ((const float4*)vptr)[1];
    }

    // ---- fast scoring over this wave's 64 centroids (branchless top-2) ----
    float best[ROWS], second[ROWS];
    int   bi[ROWS];
    #pragma unroll
    for (int r = 0; r < ROWS; ++r) {
        best[r] = -3.402823466e38f; second[r] = -3.402823466e38f; bi[r] = 0;
    }

    const int c0 = w * CPW;

    // pipeline prologue: preload centroids c0, c0+1
    float4 pA0 = ((const float4*)cbf)[2 * c0];
    float4 pB0 = ((const float4*)cbf)[2 * c0 + 1];
    float4 pA1 = ((const float4*)cbf)[2 * (c0 + 1)];
    float4 pB1 = ((const float4*)cbf)[2 * (c0 + 1) + 1];
    float  pH0 = csqh[c0];
    float  pH1 = csqh[c0 + 1];

    for (int ci = 0; ci < CPW; ci += 2) {
        // ---- issue NEXT batch's 6 LDS reads (clamped, wave-uniform addr) ----
        const int cn = (ci + 2 < CPW) ? (c0 + ci + 2) : c0;   // last iter: dummy
        float4 nA0 = ((const float4*)cbf)[2 * cn];
        float4 nB0 = ((const float4*)cbf)[2 * cn + 1];
        float4 nA1 = ((const float4*)cbf)[2 * (cn + 1)];
        float4 nB1 = ((const float4*)cbf)[2 * (cn + 1) + 1];
        float  nH0 = csqh[cn];
        float  nH1 = csqh[cn + 1];

        // ---- compute CURRENT batch: 8 independent 8-deep FMA chains ----
        const int cidx0 = c0 + ci;
        const int cidx1 = c0 + ci + 1;
        float s0[ROWS], s1[ROWS];
        #pragma unroll
        for (int r = 0; r < ROWS; ++r) {
            float s = fmaf(va[r].x, pA0.x, pH0);
            s = fmaf(va[r].y, pA0.y, s);
            s = fmaf(va[r].z, pA0.z, s);
            s = fmaf(va[r].w, pA0.w, s);
            s = fmaf(vb[r].x, pB0.x, s);
            s = fmaf(vb[r].y, pB0.y, s);
            s = fmaf(vb[r].z, pB0.z, s);
            s = fmaf(vb[r].w, pB0.w, s);
            s0[r] = s;
            float u = fmaf(va[r].x, pA1.x, pH1);
            u = fmaf(va[r].y, pA1.y, u);
            u = fmaf(va[r].z, pA1.z, u);
            u = fmaf(va[r].w, pA1.w, u);
            u = fmaf(vb[r].x, pB1.x, u);
            u = fmaf(vb[r].y, pB1.y, u);
            u = fmaf(vb[r].z, pB1.z, u);
            u = fmaf(vb[r].w, pB1.w, u);
            s1[r] = u;
        }
        // tracker updates strictly in centroid order per row: c, then c+1
        // (bit-exact match to the validated sequential scan)
        #pragma unroll
        for (int r = 0; r < ROWS; ++r) {
            bool gt = s0[r] > best[r];
            second[r] = fmaxf(second[r], fminf(s0[r], best[r]));
            bi[r]     = gt ? cidx0 : bi[r];
            best[r]   = fmaxf(s0[r], best[r]);
        }
        #pragma unroll
        for (int r = 0; r < ROWS; ++r) {
            bool gt = s1[r] > best[r];
            second[r] = fmaxf(second[r], fminf(s1[r], best[r]));
            bi[r]     = gt ? cidx1 : bi[r];
            best[r]   = fmaxf(s1[r], best[r]);
        }

        // ---- rotate buffers (pure register renaming) ----
        pA0 = nA0; pB0 = nB0; pA1 = nA1; pB1 = nB1; pH0 = nH0; pH1 = nH1;
    }

    // ---- publish partials ----
    #pragma unroll
    for (int r = 0; r < ROWS; ++r) {
        part_bs[w][r][l] = make_float2(best[r], second[r]);
        part_i [w][r][l] = bi[r];
    }
    __syncthreads();

    // ---- merge: thread t resolves row rowbase + t (its own j == w, lane l) ----
    {
        float Bst = -3.402823466e38f, Snd = -3.402823466e38f;
        int   I   = 0;
        #pragma unroll
        for (int ww = 0; ww < WPB; ++ww) {
            float2 bs = part_bs[ww][w][l];
            int    iw = part_i [ww][w][l];
            bool gt = bs.x > Bst;                 // strict, ascending ww:
            Snd = fmaxf(Snd, fminf(bs.x, Bst));   // first (smaller c) wins ties
            Snd = fmaxf(Snd, bs.y);
            I   = gt ? iw : I;
            Bst = fmaxf(Bst, bs.x);
        }

        const int row = rowbase + t;
        int idx = I;
        if (Bst - Snd <= 2.0e-5f) {               // near-tie: exact numpy path
            const float* vptr = vecs + (size_t)row * D + (size_t)p * SD;
            float4 xa = ((const float4*)vptr)[0];
            float4 xb = ((const float4*)vptr)[1];
            float q0 = xa.x*xa.x, q1 = xa.y*xa.y, q2 = xa.z*xa.z, q3 = xa.w*xa.w;
            float q4 = xb.x*xb.x, q5 = xb.y*xb.y, q6 = xb.z*xb.z, q7 = xb.w*xb.w;
            float vsq = tree8(q0,q1,q2,q3,q4,q5,q6,q7);
            idx = exact_search(cbf, csqn, xa, xb, vsq);
        }

        float4 o0 = ((const float4*)cbf)[2 * idx];
        float4 o1 = ((const float4*)cbf)[2 * idx + 1];
        float4* op = (float4*)(out + (size_t)row * D + (size_t)p * SD);
        op[0] = o0;
        op[1] = o1;
    }
}

extern "C" void kernel_launch(void* const* d_in, const int* in_sizes, int n_in,
                              void* d_out, int out_size, void* d_ws, size_t ws_size,
                              hipStream_t stream)
{
    const float* vecs     = (const float*)d_in[0];  // [B, D] fp32
    const float* codebook = (const float*)d_in[1];  // [P, C, SD] fp32
    float*       out      = (float*)d_out;          // [B, D] fp32

    dim3 grid(P, B / (64 * ROWS));   // (96, 16) -> 1536 blocks x 4 waves
    dim3 block(TPB);
    pq_split_kernel<<<grid, block, 0, stream>>>(vecs, codebook, out);
}